// Round 2
// baseline (18280.717 us; speedup 1.0000x reference)
//
#include <hip/hip_runtime.h>
#include <cmath>

#define NALL 3072
#define NF   3056
#define NT   3056
#define NC4  764          // NT/4
#define PBUF 4            // column-sum split buffers
#define TPB  256
#define LRc  0.1f
#define AEPS 1e-8f
#define OEPS 0.1f
#define ITERS 100

__device__ __forceinline__ float sigf(float x) {
    return 1.0f / (1.0f + __expf(-x));
}

// ---------------- main per-iteration kernel: gradient + Adam on GL ----------------
// One row per block (3056 blocks) for occupancy; all global loads issued up front
// so each thread has 12 independent float4 loads in flight before the dependent
// sigmoid -> product -> barrier chain.
template<bool FIRST>
__global__ void __launch_bounds__(TPB)
step_kernel(const float* GLinit, float* GL,
            float* __restrict__ mG, float* __restrict__ vG,
            const float* __restrict__ A, const float* tau,
            float* __restrict__ Srow, float* Scol,
            float bc1i, float bc2i)
{
    __shared__ float red[8];
    const int tid  = threadIdx.x;
    const int lane = tid & 63;
    const int wv   = tid >> 6;
    const bool ok2 = tid < (NC4 - 512);   // third float4 slot valid (tid < 252)
    const float c1 = 0.5f / (float)NF;
    const float c2 = 0.5f / ((float)NF * (float)NT);

    const int i = blockIdx.x;
    const float tu = tau[i];
    const size_t g4base = (size_t)i * NC4;
    const size_t abase  = (size_t)i * NALL + 16;

    // ---- issue ALL loads up front (12 independent float4 + tau vectors) ----
    float4 gl[3], a4[3], m4[3], v4[3], tv[3];
    #pragma unroll
    for (int k = 0; k < 3; ++k) {
        if (k == 2 && !ok2) {
            gl[k] = make_float4(0.f,0.f,0.f,0.f); a4[k] = gl[k];
            m4[k] = gl[k]; v4[k] = gl[k]; tv[k] = gl[k];
            continue;
        }
        const int c4 = tid + 256*k;
        gl[k] = FIRST ? ((const float4*)GLinit)[g4base + c4]
                      : ((const float4*)GL)[g4base + c4];
        a4[k] = *(const float4*)(A + abase + 4*c4);
        tv[k] = *(const float4*)(tau + 16 + 4*c4);
        if (FIRST) { m4[k] = make_float4(0.f,0.f,0.f,0.f); v4[k] = m4[k]; }
        else { m4[k] = ((const float4*)mG)[g4base + c4];
               v4[k] = ((const float4*)vG)[g4base + c4]; }
    }

    // ---- phase 1: sigmoid + row product ----
    float4 G4[3];
    float pl = 1.0f;
    #pragma unroll
    for (int k = 0; k < 3; ++k) {
        if (k == 2 && !ok2) continue;
        float4 g;
        g.x = sigf(gl[k].x); g.y = sigf(gl[k].y);
        g.z = sigf(gl[k].z); g.w = sigf(gl[k].w);
        G4[k] = g;
        pl *= fmaf(-2.0f*a4[k].x, g.x, 1.0f);
        pl *= fmaf(-2.0f*a4[k].y, g.y, 1.0f);
        pl *= fmaf(-2.0f*a4[k].z, g.z, 1.0f);
        pl *= fmaf(-2.0f*a4[k].w, g.w, 1.0f);
    }
    // block-reduce the row product (same shuffle/order as the passing version)
    float pw = pl;
    #pragma unroll
    for (int off = 1; off < 64; off <<= 1) pw *= __shfl_xor(pw, off, 64);
    if (lane == 0) red[wv] = pw;
    __syncthreads();
    const float p = red[0]*red[1]*red[2]*red[3];
    const float c1pp = c1 * (p + 1.0f);

    // ---- phase 2: gradient + Adam update + sums ----
    float rowl = 0.0f;
    float4 cacc[3];
    #pragma unroll
    for (int k = 0; k < 3; ++k) cacc[k] = make_float4(0.f,0.f,0.f,0.f);

    #pragma unroll
    for (int k = 0; k < 3; ++k) {
        if (k == 2 && !ok2) continue;
        const int c4 = tid + 256*k;
        const size_t idx4 = g4base + c4;
        float4 glo, mo, vo;
        #define COMP(FLD) { \
            const float g = G4[k].FLD; \
            const float a = a4[k].FLD; \
            const float f = fmaf(-2.0f*a, g, 1.0f); \
            const float po = (f != 0.0f) ? __fdividef(p, f) : 0.0f; \
            const float d = tu - tv[k].FLD + OEPS; \
            const float r = fmaxf(d, 0.0f); \
            const float gg = fmaf(c2, r*r, c1pp * po * (-2.0f*a)) * (g * (1.0f - g)); \
            const float m2 = fmaf(0.9f, m4[k].FLD, 0.1f*gg); \
            const float v2 = fmaf(0.999f, v4[k].FLD, 0.001f*gg*gg); \
            const float den = __fsqrt_rn(v2 * bc2i) + AEPS; \
            glo.FLD = gl[k].FLD - LRc * (m2 * bc1i) / den; \
            mo.FLD = m2; vo.FLD = v2; \
            const float w = g * r; \
            rowl += w; cacc[k].FLD += w; }
        COMP(x) COMP(y) COMP(z) COMP(w)
        #undef COMP
        ((float4*)GL)[idx4] = glo;
        ((float4*)mG)[idx4] = mo;
        ((float4*)vG)[idx4] = vo;
    }

    float sw = rowl;
    #pragma unroll
    for (int off = 1; off < 64; off <<= 1) sw += __shfl_xor(sw, off, 64);
    if (lane == 0) red[4+wv] = sw;
    __syncthreads();
    if (tid == 0) Srow[i] = (red[4]+red[5]) + (red[6]+red[7]);

    // one atomic per owned column
    float* sc = Scol + (size_t)(blockIdx.x & (PBUF-1)) * NALL;
    #pragma unroll
    for (int k = 0; k < 3; ++k) {
        if (k == 2 && !ok2) continue;
        const int c = 4*(tid + 256*k);
        atomicAdd(sc + c + 0, cacc[k].x);
        atomicAdd(sc + c + 1, cacc[k].y);
        atomicAdd(sc + c + 2, cacc[k].z);
        atomicAdd(sc + c + 3, cacc[k].w);
    }
}

// ---------------- tau Adam update (+ zero the other Scol buffer) ----------------
template<bool FIRST>
__global__ void __launch_bounds__(TPB)
tau_kernel(const float* tinit, float* tauw,
           float* __restrict__ mt, float* __restrict__ vt,
           const float* __restrict__ Srow, const float* __restrict__ ScolCur,
           float* __restrict__ ScolNxt, float bc1i, float bc2i)
{
    const int k = blockIdx.x * TPB + threadIdx.x;
    if (k >= NALL) return;
    const float ct = 1.0f / ((float)NF * (float)NT);
    float g = 0.0f;
    if (k < NF) g = Srow[k];
    if (k >= 16) {
        const int j = k - 16;
        g -= ((ScolCur[j] + ScolCur[NALL + j]) + (ScolCur[2*NALL + j] + ScolCur[3*NALL + j]));
    }
    g *= ct;
    const float t0 = FIRST ? tinit[k] : tauw[k];
    const float m0 = FIRST ? 0.0f : mt[k];
    const float v0 = FIRST ? 0.0f : vt[k];
    const float m2 = fmaf(0.9f, m0, 0.1f*g);
    const float v2 = fmaf(0.999f, v0, 0.001f*g*g);
    const float den = __fsqrt_rn(v2 * bc2i) + AEPS;
    tauw[k] = t0 - LRc * (m2 * bc1i) / den;
    mt[k] = m2; vt[k] = v2;
    #pragma unroll
    for (int pz = 0; pz < PBUF; ++pz) ScolNxt[(size_t)pz*NALL + k] = 0.0f;
}

// ---------------- final loss ----------------
__global__ void __launch_bounds__(TPB)
loss_kernel(const float* __restrict__ GL, const float* __restrict__ A,
            const float* __restrict__ tau, float* __restrict__ out)
{
    __shared__ float red[8];
    const int tid = threadIdx.x;
    const int lane = tid & 63, wv = tid >> 6;
    const bool ok2 = tid < (NC4 - 512);
    const int i = blockIdx.x;
    const float tu = tau[i];
    const size_t g4base = (size_t)i * NC4;
    const size_t abase  = (size_t)i * NALL + 16;
    float pl = 1.0f, sl = 0.0f;
    #pragma unroll
    for (int k = 0; k < 3; ++k) {
        if (k == 2 && !ok2) continue;
        const int c4 = tid + 256*k;
        float4 gl = ((const float4*)GL)[g4base + c4];
        float4 a  = *(const float4*)(A + abase + 4*c4);
        float4 tv = *(const float4*)(tau + 16 + 4*c4);
        #define LCOMP(FLD) { \
            const float g = sigf(gl.FLD); \
            pl *= fmaf(-2.0f*a.FLD, g, 1.0f); \
            const float r = fmaxf(tu - tv.FLD + OEPS, 0.0f); \
            sl += g * r * r; }
        LCOMP(x) LCOMP(y) LCOMP(z) LCOMP(w)
        #undef LCOMP
    }
    float pw = pl, sw = sl;
    #pragma unroll
    for (int off = 1; off < 64; off <<= 1) {
        pw *= __shfl_xor(pw, off, 64);
        sw += __shfl_xor(sw, off, 64);
    }
    if (lane == 0) { red[wv] = pw; red[4+wv] = sw; }
    __syncthreads();
    if (tid == 0) {
        const float p = red[0]*red[1]*red[2]*red[3];
        const float s = (red[4]+red[5]) + (red[6]+red[7]);
        const float v = 0.25f*(p+1.0f)*(p+1.0f)*(1.0f/(float)NF)
                      + 0.5f*s*(1.0f/((float)NF*(float)NT));
        atomicAdd(out, v);
    }
}

// ---------------- host ----------------
extern "C" void kernel_launch(void* const* d_in, const int* in_sizes, int n_in,
                              void* d_out, int out_size, void* d_ws, size_t ws_size,
                              hipStream_t stream)
{
    const float* A        = (const float*)d_in[0];
    const float* tau_init = (const float*)d_in[1];
    const float* GL_init  = (const float*)d_in[2];

    const size_t mat = (size_t)NF * NT;
    float* GL   = (float*)d_ws;
    float* mG   = GL + mat;
    float* vG   = mG + mat;
    float* tauw = vG + mat;
    float* mt   = tauw + NALL;
    float* vt   = mt + NALL;
    float* Srow = vt + NALL;
    float* Scol = Srow + NALL;   // 2 * PBUF * NALL floats

    hipMemsetAsync(Scol, 0, (size_t)2 * PBUF * NALL * sizeof(float), stream);
    hipMemsetAsync(d_out, 0, (size_t)out_size * sizeof(float), stream);

    for (int it = 1; it <= ITERS; ++it) {
        const float bc1i = (float)(1.0 / (1.0 - pow(0.9,   (double)it)));
        const float bc2i = (float)(1.0 / (1.0 - pow(0.999, (double)it)));
        float* scCur = Scol + (size_t)(it & 1) * PBUF * NALL;
        float* scNxt = Scol + (size_t)((it + 1) & 1) * PBUF * NALL;
        if (it == 1) {
            step_kernel<true><<<NF, TPB, 0, stream>>>(GL_init, GL, mG, vG, A, tau_init,
                                                      Srow, scCur, bc1i, bc2i);
            tau_kernel<true><<<NALL/TPB, TPB, 0, stream>>>(tau_init, tauw, mt, vt,
                                                           Srow, scCur, scNxt, bc1i, bc2i);
        } else {
            step_kernel<false><<<NF, TPB, 0, stream>>>(nullptr, GL, mG, vG, A, tauw,
                                                       Srow, scCur, bc1i, bc2i);
            tau_kernel<false><<<NALL/TPB, TPB, 0, stream>>>(nullptr, tauw, mt, vt,
                                                            Srow, scCur, scNxt, bc1i, bc2i);
        }
    }
    loss_kernel<<<NF, TPB, 0, stream>>>(GL, A, tauw, (float*)d_out);
}

// Round 3
// 8669.712 us; speedup vs baseline: 2.1086x; 2.1086x over previous
//
#include <hip/hip_runtime.h>
#include <cmath>

#define NALL 3072
#define NF   3056
#define NT   3056
#define NC4  764          // NT/4
#define RPB  4            // rows per block
#define NBLK (NF/RPB)     // 764 blocks
#define PBUF 4            // column-sum split buffers
#define TPB  256
#define LRc  0.1f
#define AEPS 1e-8f
#define OEPS 0.1f
#define ITERS 100

__device__ __forceinline__ float sigf(float x) {
    return 1.0f / (1.0f + __expf(-x));
}

// ---------------- main per-iteration kernel: gradient + Adam on GL ----------------
// RPB=4 rows/block (764 blocks -> 2.33M column atomics, the known-good count).
// Software pipeline: row rr's body FIRST issues all 12 float4 loads for row rr+1,
// then computes phase 1 / barrier / phase 2 on row rr's registers. The barrier's
// vmcnt drain lands on loads that already had a phase-1's worth of latency cover.
template<bool FIRST>
__global__ void __launch_bounds__(TPB, 3)
step_kernel(const float* GLsrc, float* GL,
            float* __restrict__ mG, float* __restrict__ vG,
            const float* __restrict__ A, const float* __restrict__ tau,
            float* __restrict__ Srow, float* __restrict__ Scol,
            float bc1i, float bc2i)
{
    __shared__ float red[8];          // double-buffered by row parity
    const int tid  = threadIdx.x;
    const int lane = tid & 63;
    const int wv   = tid >> 6;
    const bool ok2 = tid < (NC4 - 512);   // third float4 slot valid (tid < 252)
    const float c1 = 0.5f / (float)NF;
    const float c2 = 0.5f / ((float)NF * (float)NT);

    const int i0 = blockIdx.x * RPB;

    // ---- loads issued up front: tau (rows + cols) and row 0's operands ----
    const float4 tu4 = *(const float4*)(tau + i0);
    float4 tv[3];
    tv[0] = *(const float4*)(tau + 16 + 4 * tid);
    tv[1] = *(const float4*)(tau + 16 + 4 * (tid + 256));
    tv[2] = ok2 ? *(const float4*)(tau + 16 + 4 * (tid + 512)) : make_float4(0.f,0.f,0.f,0.f);
    const float tuarr[4] = {tu4.x, tu4.y, tu4.z, tu4.w};

    float4 gl[3], a4[3], m4[3], v4[3];
    {
        const size_t g4b = (size_t)i0 * NC4;
        const size_t ab  = (size_t)i0 * NALL + 16;
        #pragma unroll
        for (int k = 0; k < 3; ++k) {
            if (k == 2 && !ok2) {
                gl[k] = make_float4(0.f,0.f,0.f,0.f);
                a4[k] = gl[k]; m4[k] = gl[k]; v4[k] = gl[k];
                continue;
            }
            const int c4 = tid + 256*k;
            gl[k] = FIRST ? ((const float4*)GLsrc)[g4b + c4]
                          : ((const float4*)GL)[g4b + c4];
            a4[k] = *(const float4*)(A + ab + 4*c4);
            if (FIRST) { m4[k] = make_float4(0.f,0.f,0.f,0.f); v4[k] = m4[k]; }
            else { m4[k] = ((const float4*)mG)[g4b + c4];
                   v4[k] = ((const float4*)vG)[g4b + c4]; }
        }
    }

    float4 cacc[3];
    #pragma unroll
    for (int k = 0; k < 3; ++k) cacc[k] = make_float4(0.f,0.f,0.f,0.f);

    #pragma unroll
    for (int rr = 0; rr < RPB; ++rr) {
        const int i = i0 + rr;
        const size_t g4base = (size_t)i * NC4;

        // ---- 1. prefetch row rr+1 (issued before any compute on row rr) ----
        float4 ngl[3], na4[3], nm4[3], nv4[3];
        if (rr + 1 < RPB) {
            const size_t ng4b = (size_t)(i+1) * NC4;
            const size_t nab  = (size_t)(i+1) * NALL + 16;
            #pragma unroll
            for (int k = 0; k < 3; ++k) {
                if (k == 2 && !ok2) continue;
                const int c4 = tid + 256*k;
                ngl[k] = FIRST ? ((const float4*)GLsrc)[ng4b + c4]
                               : ((const float4*)GL)[ng4b + c4];
                na4[k] = *(const float4*)(A + nab + 4*c4);
                if (FIRST) { nm4[k] = make_float4(0.f,0.f,0.f,0.f); nv4[k] = nm4[k]; }
                else { nm4[k] = ((const float4*)mG)[ng4b + c4];
                       nv4[k] = ((const float4*)vG)[ng4b + c4]; }
            }
        }

        // ---- 2. phase 1: sigmoid + row product (registers only) ----
        const float tu = tuarr[rr];
        float4 G4[3];
        float pl = 1.0f;
        #pragma unroll
        for (int k = 0; k < 3; ++k) {
            if (k == 2 && !ok2) continue;
            float4 g;
            g.x = sigf(gl[k].x); g.y = sigf(gl[k].y);
            g.z = sigf(gl[k].z); g.w = sigf(gl[k].w);
            G4[k] = g;
            pl *= fmaf(-2.0f*a4[k].x, g.x, 1.0f);
            pl *= fmaf(-2.0f*a4[k].y, g.y, 1.0f);
            pl *= fmaf(-2.0f*a4[k].z, g.z, 1.0f);
            pl *= fmaf(-2.0f*a4[k].w, g.w, 1.0f);
        }
        float pw = pl;
        #pragma unroll
        for (int off = 1; off < 64; off <<= 1) pw *= __shfl_xor(pw, off, 64);
        const int rb = (rr & 1) * 4;
        if (lane == 0) red[rb + wv] = pw;
        __syncthreads();
        const float p = red[rb]*red[rb+1]*red[rb+2]*red[rb+3];
        const float c1pp = c1 * (p + 1.0f);

        // ---- 3. phase 2: gradient + Adam + stores (all operands in regs) ----
        float rowl = 0.0f;
        #pragma unroll
        for (int k = 0; k < 3; ++k) {
            if (k == 2 && !ok2) continue;
            const int c4 = tid + 256*k;
            const size_t idx4 = g4base + c4;
            float4 glo, mo, vo;
            #define COMP(FLD) { \
                const float g = G4[k].FLD; \
                const float a = a4[k].FLD; \
                const float f = fmaf(-2.0f*a, g, 1.0f); \
                const float po = (f != 0.0f) ? __fdividef(p, f) : 0.0f; \
                const float d = tu - tv[k].FLD + OEPS; \
                const float r = fmaxf(d, 0.0f); \
                const float gg = fmaf(c2, r*r, c1pp * po * (-2.0f*a)) * (g * (1.0f - g)); \
                const float m2 = fmaf(0.9f, m4[k].FLD, 0.1f*gg); \
                const float v2 = fmaf(0.999f, v4[k].FLD, 0.001f*gg*gg); \
                const float den = __fsqrt_rn(v2 * bc2i) + AEPS; \
                glo.FLD = gl[k].FLD - LRc * (m2 * bc1i) / den; \
                mo.FLD = m2; vo.FLD = v2; \
                const float w = g * r; \
                rowl += w; cacc[k].FLD += w; }
            COMP(x) COMP(y) COMP(z) COMP(w)
            #undef COMP
            ((float4*)GL)[idx4] = glo;
            ((float4*)mG)[idx4] = mo;
            ((float4*)vG)[idx4] = vo;
        }

        // ---- 4. row sum: per-wave reduce + one atomic per wave ----
        float sw = rowl;
        #pragma unroll
        for (int off = 1; off < 64; off <<= 1) sw += __shfl_xor(sw, off, 64);
        if (lane == 0) atomicAdd(Srow + i, sw);

        // ---- 5. rotate next -> current ----
        if (rr + 1 < RPB) {
            #pragma unroll
            for (int k = 0; k < 3; ++k) {
                gl[k] = ngl[k]; a4[k] = na4[k]; m4[k] = nm4[k]; v4[k] = nv4[k];
            }
        }
    }

    // one atomic per owned column (accumulated over RPB rows in registers)
    float* sc = Scol + (size_t)(blockIdx.x & (PBUF-1)) * NALL;
    #pragma unroll
    for (int k = 0; k < 3; ++k) {
        if (k == 2 && !ok2) continue;
        const int c = 4*(tid + 256*k);
        atomicAdd(sc + c + 0, cacc[k].x);
        atomicAdd(sc + c + 1, cacc[k].y);
        atomicAdd(sc + c + 2, cacc[k].z);
        atomicAdd(sc + c + 3, cacc[k].w);
    }
}

// ---------------- tau Adam update (+ zero next step's Srow/Scol buffers) ----------------
template<bool FIRST>
__global__ void __launch_bounds__(TPB)
tau_kernel(const float* tinit, float* tauw,
           float* __restrict__ mt, float* __restrict__ vt,
           const float* __restrict__ Srow, const float* __restrict__ ScolCur,
           float* __restrict__ ScolNxt, float* __restrict__ SrowNxt,
           float bc1i, float bc2i)
{
    const int k = blockIdx.x * TPB + threadIdx.x;
    if (k >= NALL) return;
    const float ct = 1.0f / ((float)NF * (float)NT);
    float g = 0.0f;
    if (k < NF) g = Srow[k];
    if (k >= 16) {
        const int j = k - 16;
        g -= ((ScolCur[j] + ScolCur[NALL + j]) + (ScolCur[2*NALL + j] + ScolCur[3*NALL + j]));
    }
    g *= ct;
    const float t0 = FIRST ? tinit[k] : tauw[k];
    const float m0 = FIRST ? 0.0f : mt[k];
    const float v0 = FIRST ? 0.0f : vt[k];
    const float m2 = fmaf(0.9f, m0, 0.1f*g);
    const float v2 = fmaf(0.999f, v0, 0.001f*g*g);
    const float den = __fsqrt_rn(v2 * bc2i) + AEPS;
    tauw[k] = t0 - LRc * (m2 * bc1i) / den;
    mt[k] = m2; vt[k] = v2;
    SrowNxt[k] = 0.0f;
    #pragma unroll
    for (int pz = 0; pz < PBUF; ++pz) ScolNxt[(size_t)pz*NALL + k] = 0.0f;
}

// ---------------- final loss ----------------
__global__ void __launch_bounds__(TPB)
loss_kernel(const float* __restrict__ GL, const float* __restrict__ A,
            const float* __restrict__ tau, float* __restrict__ out)
{
    __shared__ float red[8];
    const int tid = threadIdx.x;
    const int lane = tid & 63, wv = tid >> 6;
    const bool ok2 = tid < (NC4 - 512);
    const int i = blockIdx.x;
    const float tu = tau[i];
    const size_t g4base = (size_t)i * NC4;
    const size_t abase  = (size_t)i * NALL + 16;
    float pl = 1.0f, sl = 0.0f;
    #pragma unroll
    for (int k = 0; k < 3; ++k) {
        if (k == 2 && !ok2) continue;
        const int c4 = tid + 256*k;
        float4 gl = ((const float4*)GL)[g4base + c4];
        float4 a  = *(const float4*)(A + abase + 4*c4);
        float4 tv = *(const float4*)(tau + 16 + 4*c4);
        #define LCOMP(FLD) { \
            const float g = sigf(gl.FLD); \
            pl *= fmaf(-2.0f*a.FLD, g, 1.0f); \
            const float r = fmaxf(tu - tv.FLD + OEPS, 0.0f); \
            sl += g * r * r; }
        LCOMP(x) LCOMP(y) LCOMP(z) LCOMP(w)
        #undef LCOMP
    }
    float pw = pl, sw = sl;
    #pragma unroll
    for (int off = 1; off < 64; off <<= 1) {
        pw *= __shfl_xor(pw, off, 64);
        sw += __shfl_xor(sw, off, 64);
    }
    if (lane == 0) { red[wv] = pw; red[4+wv] = sw; }
    __syncthreads();
    if (tid == 0) {
        const float p = red[0]*red[1]*red[2]*red[3];
        const float s = (red[4]+red[5]) + (red[6]+red[7]);
        const float v = 0.25f*(p+1.0f)*(p+1.0f)*(1.0f/(float)NF)
                      + 0.5f*s*(1.0f/((float)NF*(float)NT));
        atomicAdd(out, v);
    }
}

// ---------------- host ----------------
extern "C" void kernel_launch(void* const* d_in, const int* in_sizes, int n_in,
                              void* d_out, int out_size, void* d_ws, size_t ws_size,
                              hipStream_t stream)
{
    const float* A        = (const float*)d_in[0];
    const float* tau_init = (const float*)d_in[1];
    const float* GL_init  = (const float*)d_in[2];

    const size_t mat = (size_t)NF * NT;
    float* GL   = (float*)d_ws;
    float* mG   = GL + mat;
    float* vG   = mG + mat;
    float* tauw = vG + mat;
    float* mt   = tauw + NALL;
    float* vt   = mt + NALL;
    float* Srow = vt + NALL;     // 2 * NALL (double-buffered)
    float* Scol = Srow + 2*NALL; // 2 * PBUF * NALL (double-buffered)

    // zero both parities of Srow and Scol (contiguous), and the output scalar
    hipMemsetAsync(Srow, 0, (size_t)(2 + 2*PBUF) * NALL * sizeof(float), stream);
    hipMemsetAsync(d_out, 0, (size_t)out_size * sizeof(float), stream);

    for (int it = 1; it <= ITERS; ++it) {
        const float bc1i = (float)(1.0 / (1.0 - pow(0.9,   (double)it)));
        const float bc2i = (float)(1.0 / (1.0 - pow(0.999, (double)it)));
        float* srCur = Srow + (size_t)(it & 1) * NALL;
        float* srNxt = Srow + (size_t)((it + 1) & 1) * NALL;
        float* scCur = Scol + (size_t)(it & 1) * PBUF * NALL;
        float* scNxt = Scol + (size_t)((it + 1) & 1) * PBUF * NALL;
        if (it == 1) {
            step_kernel<true><<<NBLK, TPB, 0, stream>>>(GL_init, GL, mG, vG, A, tau_init,
                                                        srCur, scCur, bc1i, bc2i);
            tau_kernel<true><<<NALL/TPB, TPB, 0, stream>>>(tau_init, tauw, mt, vt,
                                                           srCur, scCur, scNxt, srNxt,
                                                           bc1i, bc2i);
        } else {
            step_kernel<false><<<NBLK, TPB, 0, stream>>>(GL, GL, mG, vG, A, tauw,
                                                         srCur, scCur, bc1i, bc2i);
            tau_kernel<false><<<NALL/TPB, TPB, 0, stream>>>(nullptr, tauw, mt, vt,
                                                            srCur, scCur, scNxt, srNxt,
                                                            bc1i, bc2i);
        }
    }
    loss_kernel<<<NF, TPB, 0, stream>>>(GL, A, tauw, (float*)d_out);
}

// Round 4
// 4880.235 us; speedup vs baseline: 3.7459x; 1.7765x over previous
//
#include <hip/hip_runtime.h>
#include <cmath>

#define NALL 3072
#define NF   3056
#define NT   3056
#define NC4  764          // NT/4
#define RPB  4            // rows per block
#define NBLK (NF/RPB)     // 764 blocks
#define SPLIT 32          // column-sum reduction slices
#define RPS  ((NBLK + SPLIT - 1) / SPLIT)   // 24 rows per slice
#define TPB  256
#define LRc  0.1f
#define AEPS 1e-8f
#define OEPS 0.1f
#define ITERS 100

__device__ __forceinline__ float sigf(float x) {
    return 1.0f / (1.0f + __expf(-x));
}

// ---------------- main per-iteration kernel: gradient + Adam on GL ----------------
// Round-1 structure (known 94us), but ZERO atomics: per-block column partials go
// to a private Pcol row with plain coalesced float4 stores; row sums direct-store.
template<bool FIRST>
__global__ void __launch_bounds__(TPB)
step_kernel(const float* GLsrc, float* GL,
            float* __restrict__ mG, float* __restrict__ vG,
            const float* __restrict__ A, const float* __restrict__ tau,
            float* __restrict__ Srow, float* __restrict__ Pcol,
            float bc1i, float bc2i)
{
    __shared__ float red[8];
    const int tid  = threadIdx.x;
    const int lane = tid & 63;
    const int wv   = tid >> 6;
    const bool ok2 = tid < (NC4 - 512);   // third float4 slot valid (tid < 252)
    const float c1 = 0.5f / (float)NF;
    const float c2 = 0.5f / ((float)NF * (float)NT);

    // tau_v for this thread's 12 columns
    float4 tv[3];
    tv[0] = *(const float4*)(tau + 16 + 4 * tid);
    tv[1] = *(const float4*)(tau + 16 + 4 * (tid + 256));
    tv[2] = ok2 ? *(const float4*)(tau + 16 + 4 * (tid + 512)) : make_float4(0.f,0.f,0.f,0.f);

    float4 cacc[3];
    #pragma unroll
    for (int k = 0; k < 3; ++k) cacc[k] = make_float4(0.f,0.f,0.f,0.f);

    for (int rr = 0; rr < RPB; ++rr) {
        const int i = blockIdx.x * RPB + rr;
        const float tu = tau[i];
        const size_t g4base = (size_t)i * NC4;
        const size_t abase  = (size_t)i * NALL + 16;

        // ---- loads for this row (12 independent float4) ----
        float4 gl[3], a4[3], m4[3], v4[3];
        #pragma unroll
        for (int k = 0; k < 3; ++k) {
            if (k == 2 && !ok2) continue;
            const int c4 = tid + 256*k;
            gl[k] = FIRST ? ((const float4*)GLsrc)[g4base + c4]
                          : ((const float4*)GL)[g4base + c4];
            a4[k] = *(const float4*)(A + abase + 4*c4);
            if (FIRST) { m4[k] = make_float4(0.f,0.f,0.f,0.f); v4[k] = m4[k]; }
            else { m4[k] = ((const float4*)mG)[g4base + c4];
                   v4[k] = ((const float4*)vG)[g4base + c4]; }
        }

        // ---- phase 1: sigmoid + row product ----
        float4 G4[3];
        float pl = 1.0f;
        #pragma unroll
        for (int k = 0; k < 3; ++k) {
            if (k == 2 && !ok2) continue;
            float4 g;
            g.x = sigf(gl[k].x); g.y = sigf(gl[k].y);
            g.z = sigf(gl[k].z); g.w = sigf(gl[k].w);
            G4[k] = g;
            pl *= fmaf(-2.0f*a4[k].x, g.x, 1.0f);
            pl *= fmaf(-2.0f*a4[k].y, g.y, 1.0f);
            pl *= fmaf(-2.0f*a4[k].z, g.z, 1.0f);
            pl *= fmaf(-2.0f*a4[k].w, g.w, 1.0f);
        }
        float pw = pl;
        #pragma unroll
        for (int off = 1; off < 64; off <<= 1) pw *= __shfl_xor(pw, off, 64);
        __syncthreads();                       // protect red[] reuse across rows
        if (lane == 0) red[wv] = pw;
        __syncthreads();
        const float p = red[0]*red[1]*red[2]*red[3];
        const float c1pp = c1 * (p + 1.0f);

        // ---- phase 2: gradient + Adam + stores ----
        float rowl = 0.0f;
        #pragma unroll
        for (int k = 0; k < 3; ++k) {
            if (k == 2 && !ok2) continue;
            const int c4 = tid + 256*k;
            const size_t idx4 = g4base + c4;
            float4 glo, mo, vo;
            #define COMP(FLD) { \
                const float g = G4[k].FLD; \
                const float a = a4[k].FLD; \
                const float f = fmaf(-2.0f*a, g, 1.0f); \
                const float po = (f != 0.0f) ? __fdividef(p, f) : 0.0f; \
                const float d = tu - tv[k].FLD + OEPS; \
                const float r = fmaxf(d, 0.0f); \
                const float gg = fmaf(c2, r*r, c1pp * po * (-2.0f*a)) * (g * (1.0f - g)); \
                const float m2 = fmaf(0.9f, m4[k].FLD, 0.1f*gg); \
                const float v2 = fmaf(0.999f, v4[k].FLD, 0.001f*gg*gg); \
                const float den = __fsqrt_rn(v2 * bc2i) + AEPS; \
                glo.FLD = gl[k].FLD - LRc * (m2 * bc1i) / den; \
                mo.FLD = m2; vo.FLD = v2; \
                const float w = g * r; \
                rowl += w; cacc[k].FLD += w; }
            COMP(x) COMP(y) COMP(z) COMP(w)
            #undef COMP
            ((float4*)GL)[idx4] = glo;
            ((float4*)mG)[idx4] = mo;
            ((float4*)vG)[idx4] = vo;
        }

        float sw = rowl;
        #pragma unroll
        for (int off = 1; off < 64; off <<= 1) sw += __shfl_xor(sw, off, 64);
        if (lane == 0) red[4+wv] = sw;
        __syncthreads();
        if (tid == 0) Srow[i] = (red[4]+red[5]) + (red[6]+red[7]);
    }

    // private column partials: plain coalesced float4 stores (NO atomics)
    float* pc = Pcol + (size_t)blockIdx.x * NT;
    #pragma unroll
    for (int k = 0; k < 3; ++k) {
        if (k == 2 && !ok2) continue;
        *(float4*)(pc + 4*(tid + 256*k)) = cacc[k];
    }
}

// ---------------- column-partial reduction: 764 rows -> SPLIT slices ----------------
__global__ void __launch_bounds__(TPB)
colsum_kernel(const float* __restrict__ Pcol, float* __restrict__ Pcol2)
{
    const int c = blockIdx.x * TPB + threadIdx.x;
    if (c >= NT) return;
    const int s  = blockIdx.y;
    const int r0 = s * RPS;
    const int r1 = (r0 + RPS < NBLK) ? (r0 + RPS) : NBLK;
    float a[8];
    #pragma unroll
    for (int u = 0; u < 8; ++u) a[u] = 0.0f;
    const float* p = Pcol + (size_t)r0 * NT + c;
    int r = r0;
    for (; r + 8 <= r1; r += 8) {
        #pragma unroll
        for (int u = 0; u < 8; ++u) a[u] += p[(size_t)u * NT];
        p += (size_t)8 * NT;
    }
    for (; r < r1; ++r) { a[0] += *p; p += NT; }
    Pcol2[(size_t)s * NT + c] =
        ((a[0]+a[1])+(a[2]+a[3])) + ((a[4]+a[5])+(a[6]+a[7]));
}

// ---------------- tau Adam update ----------------
template<bool FIRST>
__global__ void __launch_bounds__(TPB)
tau_kernel(const float* tinit, float* tauw,
           float* __restrict__ mt, float* __restrict__ vt,
           const float* __restrict__ Srow, const float* __restrict__ Pcol2,
           float bc1i, float bc2i)
{
    const int k = blockIdx.x * TPB + threadIdx.x;
    if (k >= NALL) return;
    const float ct = 1.0f / ((float)NF * (float)NT);
    float g = 0.0f;
    if (k < NF) g = Srow[k];
    if (k >= 16) {
        const int j = k - 16;
        float s = 0.0f;
        #pragma unroll
        for (int t = 0; t < SPLIT; ++t) s += Pcol2[(size_t)t * NT + j];
        g -= s;
    }
    g *= ct;
    const float t0 = FIRST ? tinit[k] : tauw[k];
    const float m0 = FIRST ? 0.0f : mt[k];
    const float v0 = FIRST ? 0.0f : vt[k];
    const float m2 = fmaf(0.9f, m0, 0.1f*g);
    const float v2 = fmaf(0.999f, v0, 0.001f*g*g);
    const float den = __fsqrt_rn(v2 * bc2i) + AEPS;
    tauw[k] = t0 - LRc * (m2 * bc1i) / den;
    mt[k] = m2; vt[k] = v2;
}

// ---------------- final loss ----------------
__global__ void __launch_bounds__(TPB)
loss_kernel(const float* __restrict__ GL, const float* __restrict__ A,
            const float* __restrict__ tau, float* __restrict__ out)
{
    __shared__ float red[8];
    const int tid = threadIdx.x;
    const int lane = tid & 63, wv = tid >> 6;
    const bool ok2 = tid < (NC4 - 512);
    const int i = blockIdx.x;
    const float tu = tau[i];
    const size_t g4base = (size_t)i * NC4;
    const size_t abase  = (size_t)i * NALL + 16;
    float pl = 1.0f, sl = 0.0f;
    #pragma unroll
    for (int k = 0; k < 3; ++k) {
        if (k == 2 && !ok2) continue;
        const int c4 = tid + 256*k;
        float4 gl = ((const float4*)GL)[g4base + c4];
        float4 a  = *(const float4*)(A + abase + 4*c4);
        float4 tv = *(const float4*)(tau + 16 + 4*c4);
        #define LCOMP(FLD) { \
            const float g = sigf(gl.FLD); \
            pl *= fmaf(-2.0f*a.FLD, g, 1.0f); \
            const float r = fmaxf(tu - tv.FLD + OEPS, 0.0f); \
            sl += g * r * r; }
        LCOMP(x) LCOMP(y) LCOMP(z) LCOMP(w)
        #undef LCOMP
    }
    float pw = pl, sw = sl;
    #pragma unroll
    for (int off = 1; off < 64; off <<= 1) {
        pw *= __shfl_xor(pw, off, 64);
        sw += __shfl_xor(sw, off, 64);
    }
    if (lane == 0) { red[wv] = pw; red[4+wv] = sw; }
    __syncthreads();
    if (tid == 0) {
        const float p = red[0]*red[1]*red[2]*red[3];
        const float s = (red[4]+red[5]) + (red[6]+red[7]);
        const float v = 0.25f*(p+1.0f)*(p+1.0f)*(1.0f/(float)NF)
                      + 0.5f*s*(1.0f/((float)NF*(float)NT));
        atomicAdd(out, v);
    }
}

// ---------------- host ----------------
extern "C" void kernel_launch(void* const* d_in, const int* in_sizes, int n_in,
                              void* d_out, int out_size, void* d_ws, size_t ws_size,
                              hipStream_t stream)
{
    const float* A        = (const float*)d_in[0];
    const float* tau_init = (const float*)d_in[1];
    const float* GL_init  = (const float*)d_in[2];

    const size_t mat = (size_t)NF * NT;
    float* GL    = (float*)d_ws;
    float* mG    = GL + mat;
    float* vG    = mG + mat;
    float* tauw  = vG + mat;
    float* mt    = tauw + NALL;
    float* vt    = mt + NALL;
    float* Srow  = vt + NALL;
    float* Pcol  = Srow + NALL;                 // NBLK * NT floats (9.3 MB)
    float* Pcol2 = Pcol + (size_t)NBLK * NT;    // SPLIT * NT floats

    hipMemsetAsync(d_out, 0, (size_t)out_size * sizeof(float), stream);

    const dim3 csGrid((NT + TPB - 1) / TPB, SPLIT);

    for (int it = 1; it <= ITERS; ++it) {
        const float bc1i = (float)(1.0 / (1.0 - pow(0.9,   (double)it)));
        const float bc2i = (float)(1.0 / (1.0 - pow(0.999, (double)it)));
        if (it == 1) {
            step_kernel<true><<<NBLK, TPB, 0, stream>>>(GL_init, GL, mG, vG, A, tau_init,
                                                        Srow, Pcol, bc1i, bc2i);
            colsum_kernel<<<csGrid, TPB, 0, stream>>>(Pcol, Pcol2);
            tau_kernel<true><<<NALL/TPB, TPB, 0, stream>>>(tau_init, tauw, mt, vt,
                                                           Srow, Pcol2, bc1i, bc2i);
        } else {
            step_kernel<false><<<NBLK, TPB, 0, stream>>>(GL, GL, mG, vG, A, tauw,
                                                         Srow, Pcol, bc1i, bc2i);
            colsum_kernel<<<csGrid, TPB, 0, stream>>>(Pcol, Pcol2);
            tau_kernel<false><<<NALL/TPB, TPB, 0, stream>>>(nullptr, tauw, mt, vt,
                                                            Srow, Pcol2, bc1i, bc2i);
        }
    }
    loss_kernel<<<NF, TPB, 0, stream>>>(GL, A, tauw, (float*)d_out);
}